// Round 1
// baseline (2530.142 us; speedup 1.0000x reference)
//
#include <hip/hip_runtime.h>
#include <cfloat>

#define BB 4
#define NN 4096
#define KK 16

// ---------------- pc (B,N,6) -> feat0 (B,6,N) ----------------
__global__ __launch_bounds__(256) void transpose_pc_kernel(const float* __restrict__ pc,
                                                           float* __restrict__ feat0) {
  int j = blockIdx.x * 256 + threadIdx.x;
  if (j >= BB * 6 * NN) return;
  int n = j & (NN - 1);
  int c = (j / NN) % 6;
  int b = j / (6 * NN);
  feat0[j] = pc[((size_t)b * NN + n) * 6 + c];
}

// ---------------- KNN: top-16 nearest (ascending d2, ties -> lower index) ----------------
__global__ __launch_bounds__(256) void knn_kernel(const float* __restrict__ pc,
                                                  int* __restrict__ idx) {
  __shared__ float sx[256], sy[256], sz[256], sq[256];
  const int b = blockIdx.y;
  const int n = blockIdx.x * 256 + threadIdx.x;
  const float* pcb = pc + (size_t)b * NN * 6;
  const float xn = pcb[n * 6 + 0];
  const float yn = pcb[n * 6 + 1];
  const float zn = pcb[n * 6 + 2];
  const float sqn = xn * xn + yn * yn + zn * zn;
  float dist[KK];
  int nid[KK];
#pragma unroll
  for (int i = 0; i < KK; ++i) { dist[i] = FLT_MAX; nid[i] = 0; }
  for (int tile = 0; tile < NN; tile += 256) {
    const int m = tile + threadIdx.x;
    float x = pcb[m * 6 + 0];
    float y = pcb[m * 6 + 1];
    float z = pcb[m * 6 + 2];
    __syncthreads();
    sx[threadIdx.x] = x; sy[threadIdx.x] = y; sz[threadIdx.x] = z;
    sq[threadIdx.x] = x * x + y * y + z * z;
    __syncthreads();
    for (int j = 0; j < 256; ++j) {
      const float d2 = sqn + sq[j] - 2.0f * (xn * sx[j] + yn * sy[j] + zn * sz[j]);
      if (d2 < dist[KK - 1]) {  // strict: ties keep earlier (lower) index, matching top_k
        const int mj = tile + j;
        bool c_hi = true;  // (d2 < dist[i]) for i = KK-1, known true from guard
#pragma unroll
        for (int i = KK - 1; i > 0; --i) {
          const bool c_lo = d2 < dist[i - 1];
          const float di = c_lo ? dist[i - 1] : (c_hi ? d2 : dist[i]);
          const int ii   = c_lo ? nid[i - 1]  : (c_hi ? mj : nid[i]);
          dist[i] = di; nid[i] = ii;
          c_hi = c_lo;
        }
        if (c_hi) { dist[0] = d2; nid[0] = mj; }
      }
    }
  }
  int* orow = idx + ((size_t)b * NN + n) * KK;
#pragma unroll
  for (int i = 0; i < KK; ++i) orow[i] = nid[i];
}

// ---------------- tay_all[l][(b,n,k),t] = w1_l @ taylor(rel) + b1_l ----------------
__global__ __launch_bounds__(256) void taylor_kernel(
    const float* __restrict__ pc, const int* __restrict__ idx,
    const float* __restrict__ w1_1, const float* __restrict__ b1_1,
    const float* __restrict__ w1_2, const float* __restrict__ b1_2,
    const float* __restrict__ w1_3, const float* __restrict__ b1_3,
    const float* __restrict__ w1_4, const float* __restrict__ b1_4,
    float* __restrict__ tay) {
  const int i = blockIdx.x * 256 + threadIdx.x;
  if (i >= BB * NN * KK) return;
  const int n = (i / KK) & (NN - 1);
  const int b = i / (KK * NN);
  const float* pcb = pc + (size_t)b * NN * 6;
  const int m = idx[i];
  const float x = pcb[m * 6 + 0] - pcb[n * 6 + 0];
  const float y = pcb[m * 6 + 1] - pcb[n * 6 + 1];
  const float z = pcb[m * 6 + 2] - pcb[n * 6 + 2];
  float tb[20];
  tb[0] = 1.0f; tb[1] = x; tb[2] = y; tb[3] = z;
  tb[4] = x * x; tb[5] = x * y; tb[6] = x * z;
  tb[7] = y * y; tb[8] = y * z; tb[9] = z * z;
  tb[10] = tb[4] * x; tb[11] = tb[4] * y; tb[12] = tb[4] * z;
  tb[13] = tb[5] * y; tb[14] = tb[5] * z; tb[15] = tb[6] * z;
  tb[16] = tb[7] * y; tb[17] = tb[7] * z; tb[18] = tb[8] * z; tb[19] = tb[9] * z;
  const float* w1s[4] = {w1_1, w1_2, w1_3, w1_4};
  const float* b1s[4] = {b1_1, b1_2, b1_3, b1_4};
  const size_t tstride = (size_t)BB * NN * KK * 3;
  float* trow = tay + (size_t)i * 3;
#pragma unroll
  for (int l = 0; l < 4; ++l) {
    const float* w1 = w1s[l];
    const float* b1 = b1s[l];
#pragma unroll
    for (int c = 0; c < 3; ++c) {
      float s = b1[c];
#pragma unroll
      for (int j = 0; j < 20; ++j) s = fmaf(w1[c * 20 + j], tb[j], s);
      trow[(size_t)l * tstride + c] = s;
    }
  }
}

// ---------------- spider conv as SGEMM: out[o,p] = sum_q W[o,q] * F[q,p] ----------------
// q = (c,t,k), k fastest  ==  w2's native (cout, cin*3, 16) layout.
// F built on the fly in LDS: F[(c,t,k), p] = feat[c, idx[p,k]] * tay[p,k,t]
template <int CIN, int COUT>
__global__ __launch_bounds__(256) void conv_kernel(
    const float* __restrict__ fin, int fin_bstride,
    const float* __restrict__ w2, const float* __restrict__ b2,
    const float* __restrict__ tay, const int* __restrict__ idx,
    float* __restrict__ fout, int fout_bstride) {
  constexpr int CT = CIN * 3;
  constexpr int QTOT = CT * KK;
  __shared__ __align__(16) float Ws[KK][64];
  __shared__ __align__(16) float Fs[KK][64];
  const int b = blockIdx.z;
  const int pbase = blockIdx.x * 64;
  const int obase = blockIdx.y * 64;
  const int t = threadIdx.x;
  const int tx = t & 15;       // point micro-tile
  const int ty = t >> 4;       // channel micro-tile
  const int l64 = t & 63;      // staging row (o for W, p for F)
  const int q4 = (t >> 6) * 4; // staging k/q chunk: 0,4,8,12
  float acc[4][4];
#pragma unroll
  for (int i = 0; i < 4; ++i)
#pragma unroll
    for (int j = 0; j < 4; ++j) acc[i][j] = 0.0f;
  const float* finb = fin + (size_t)b * fin_bstride;
  const int orow = obase + l64;
  const bool ovalid = orow < COUT;
  const float* wrow = w2 + (size_t)(ovalid ? orow : 0) * QTOT + q4;
  const int4 mi = *(const int4*)(idx + ((size_t)b * NN + pbase + l64) * KK + q4);
  const float* trow = tay + ((size_t)b * NN + pbase + l64) * (KK * 3) + q4 * 3;
#pragma unroll 1
  for (int ct = 0; ct < CT; ++ct) {
    const int c = ct / 3;
    const int tt = ct - c * 3;
    float4 wv = make_float4(0.f, 0.f, 0.f, 0.f);
    if (ovalid) wv = *(const float4*)(wrow + ct * KK);
    const float* frow = finb + (size_t)c * NN;
    float4 fv;
    fv.x = frow[mi.x] * trow[0 * 3 + tt];
    fv.y = frow[mi.y] * trow[1 * 3 + tt];
    fv.z = frow[mi.z] * trow[2 * 3 + tt];
    fv.w = frow[mi.w] * trow[3 * 3 + tt];
    __syncthreads();
    Ws[q4 + 0][l64] = wv.x;
    Ws[q4 + 1][l64] = wv.y;
    Ws[q4 + 2][l64] = wv.z;
    Ws[q4 + 3][l64] = wv.w;
    Fs[q4 + 0][l64] = fv.x;
    Fs[q4 + 1][l64] = fv.y;
    Fs[q4 + 2][l64] = fv.z;
    Fs[q4 + 3][l64] = fv.w;
    __syncthreads();
#pragma unroll
    for (int qq = 0; qq < KK; ++qq) {
      float wvv[4], fvv[4];
      *(float4*)wvv = *(const float4*)&Ws[qq][ty * 4];
      *(float4*)fvv = *(const float4*)&Fs[qq][tx * 4];
#pragma unroll
      for (int i = 0; i < 4; ++i)
#pragma unroll
        for (int j = 0; j < 4; ++j)
          acc[i][j] = fmaf(wvv[i], fvv[j], acc[i][j]);
    }
  }
#pragma unroll
  for (int i = 0; i < 4; ++i) {
    const int o = obase + ty * 4 + i;
    if (o < COUT) {
      const float bias = b2[o];
      float4 r;
      r.x = fmaxf(acc[i][0] + bias, 0.0f);
      r.y = fmaxf(acc[i][1] + bias, 0.0f);
      r.z = fmaxf(acc[i][2] + bias, 0.0f);
      r.w = fmaxf(acc[i][3] + bias, 0.0f);
      *(float4*)(fout + (size_t)b * fout_bstride + (size_t)o * NN + pbase + tx * 4) = r;
    }
  }
}

// ---------------- top-2 over N per (b, channel) ----------------
__global__ __launch_bounds__(256) void top2_kernel(const float* __restrict__ pf,
                                                   float* __restrict__ cat) {
  const int row = blockIdx.x;  // b*480 + ch
  const float* p = pf + (size_t)row * NN;
  float m1 = -FLT_MAX, m2 = -FLT_MAX;
  for (int i = threadIdx.x; i < NN; i += 256) {
    const float v = p[i];
    if (v > m1) { m2 = m1; m1 = v; }
    else if (v > m2) m2 = v;
  }
#pragma unroll
  for (int off = 32; off > 0; off >>= 1) {
    const float o1 = __shfl_down(m1, off, 64);
    const float o2 = __shfl_down(m2, off, 64);
    const float nm1 = fmaxf(m1, o1);
    const float nm2 = fmaxf(fminf(m1, o1), fmaxf(m2, o2));
    m1 = nm1; m2 = nm2;
  }
  __shared__ float s1[4], s2[4];
  const int wid = threadIdx.x >> 6;
  if ((threadIdx.x & 63) == 0) { s1[wid] = m1; s2[wid] = m2; }
  __syncthreads();
  if (threadIdx.x == 0) {
    m1 = s1[0]; m2 = s2[0];
#pragma unroll
    for (int w = 1; w < 4; ++w) {
      const float o1 = s1[w], o2 = s2[w];
      const float nm1 = fmaxf(m1, o1);
      const float nm2 = fmaxf(fminf(m1, o1), fmaxf(m2, o2));
      m1 = nm1; m2 = nm2;
    }
    const int b = row / 480, ch = row % 480;
    cat[b * 960 + ch * 2 + 0] = m1;
    cat[b * 960 + ch * 2 + 1] = m2;
  }
}

extern "C" void kernel_launch(void* const* d_in, const int* in_sizes, int n_in,
                              void* d_out, int out_size, void* d_ws, size_t ws_size,
                              hipStream_t stream) {
  const float* pc = (const float*)d_in[0];
  const float* w1s[4]; const float* b1s[4]; const float* w2s[4]; const float* b2s[4];
  for (int l = 0; l < 4; ++l) {
    w1s[l] = (const float*)d_in[1 + 4 * l];
    b1s[l] = (const float*)d_in[2 + 4 * l];
    w2s[l] = (const float*)d_in[3 + 4 * l];
    b2s[l] = (const float*)d_in[4 + 4 * l];
  }
  float* ws = (float*)d_ws;
  float* feat0 = ws;                                  // B*6*N      =   98304 f
  int* idx = (int*)(ws + BB * 6 * NN);                // B*N*K      =  262144 i
  float* tay = ws + BB * 6 * NN + BB * NN * KK;       // 4*B*N*K*3  = 3145728 f
  float* cat = (float*)d_out;                         // B*960
  float* pf = (float*)d_out + BB * 960;               // (B,480,N)
  const int pfstride = 480 * NN;
  const size_t tstride = (size_t)BB * NN * KK * 3;

  transpose_pc_kernel<<<dim3((BB * 6 * NN + 255) / 256), dim3(256), 0, stream>>>(pc, feat0);
  knn_kernel<<<dim3(NN / 256, BB), dim3(256), 0, stream>>>(pc, idx);
  taylor_kernel<<<dim3((BB * NN * KK + 255) / 256), dim3(256), 0, stream>>>(
      pc, idx, w1s[0], b1s[0], w1s[1], b1s[1], w1s[2], b1s[2], w1s[3], b1s[3], tay);
  conv_kernel<6, 32><<<dim3(NN / 64, 1, BB), dim3(256), 0, stream>>>(
      feat0, 6 * NN, w2s[0], b2s[0], tay + 0 * tstride, idx, pf + (size_t)0 * NN, pfstride);
  conv_kernel<32, 64><<<dim3(NN / 64, 1, BB), dim3(256), 0, stream>>>(
      pf + (size_t)0 * NN, pfstride, w2s[1], b2s[1], tay + 1 * tstride, idx, pf + (size_t)32 * NN, pfstride);
  conv_kernel<64, 128><<<dim3(NN / 64, 2, BB), dim3(256), 0, stream>>>(
      pf + (size_t)32 * NN, pfstride, w2s[2], b2s[2], tay + 2 * tstride, idx, pf + (size_t)96 * NN, pfstride);
  conv_kernel<128, 256><<<dim3(NN / 64, 4, BB), dim3(256), 0, stream>>>(
      pf + (size_t)96 * NN, pfstride, w2s[3], b2s[3], tay + 3 * tstride, idx, pf + (size_t)224 * NN, pfstride);
  top2_kernel<<<dim3(BB * 480), dim3(256), 0, stream>>>(pf, cat);
}

// Round 2
// 743.639 us; speedup vs baseline: 3.4024x; 3.4024x over previous
//
#include <hip/hip_runtime.h>
#include <cfloat>

#define BB 4
#define NN 4096
#define KK 16
#define NPTS (BB * NN)          // 16384
#define TSTRIDE (NPTS * 48)     // per-layer tay floats: [p][t][k], t in 0..2, k in 0..15

typedef __attribute__((ext_vector_type(8))) short bf16x8;
typedef __attribute__((ext_vector_type(4))) float f32x4;
typedef unsigned int u32;

__device__ __forceinline__ unsigned short f2bf(float f) {
  u32 u = __float_as_uint(f);
  u += 0x7fffu + ((u >> 16) & 1u);  // RNE (finite values only)
  return (unsigned short)(u >> 16);
}

// ---------------- weight fp32 -> bf16, zero-padded to mpad rows ----------------
__global__ __launch_bounds__(256) void wcvt_kernel(const float* __restrict__ w2,
                                                   short* __restrict__ wb,
                                                   int cout, int total, int qtot) {
  int i = blockIdx.x * 256 + threadIdx.x;
  if (i >= total) return;
  int o = i / qtot;
  float v = (o < cout) ? w2[i] : 0.0f;
  wb[i] = (short)f2bf(v);
}

// ---------------- KNN partials: top-16 within candidate chunk cz (512 cands) ----------------
__global__ __launch_bounds__(256) void knn_part_kernel(const float* __restrict__ pc,
                                                       float* __restrict__ partd,
                                                       int* __restrict__ parti) {
  __shared__ float4 sc[256];
  const int b = blockIdx.y;
  const int cz = blockIdx.z;
  const int n = blockIdx.x * 256 + threadIdx.x;
  const float* pcb = pc + (size_t)b * NN * 6;
  const float xn = pcb[n * 6 + 0];
  const float yn = pcb[n * 6 + 1];
  const float zn = pcb[n * 6 + 2];
  const float sqn = xn * xn + yn * yn + zn * zn;
  float dist[KK];
  int nid[KK];
#pragma unroll
  for (int i = 0; i < KK; ++i) { dist[i] = FLT_MAX; nid[i] = 0; }
  for (int t4 = 0; t4 < 2; ++t4) {
    const int base = cz * 512 + t4 * 256;
    const int m0 = base + threadIdx.x;
    float x = pcb[m0 * 6 + 0];
    float y = pcb[m0 * 6 + 1];
    float z = pcb[m0 * 6 + 2];
    __syncthreads();
    sc[threadIdx.x] = make_float4(x, y, z, x * x + y * y + z * z);
    __syncthreads();
    for (int j = 0; j < 256; ++j) {
      const float4 q = sc[j];
      const float d2 = sqn + q.w - 2.0f * (xn * q.x + yn * q.y + zn * q.z);
      if (d2 < dist[KK - 1]) {  // strict: ties keep earlier (lower) index
        const int mj = base + j;
        bool c_hi = true;
#pragma unroll
        for (int i = KK - 1; i > 0; --i) {
          const bool c_lo = d2 < dist[i - 1];
          const float di = c_lo ? dist[i - 1] : (c_hi ? d2 : dist[i]);
          const int ii = c_lo ? nid[i - 1] : (c_hi ? mj : nid[i]);
          dist[i] = di; nid[i] = ii;
          c_hi = c_lo;
        }
        if (c_hi) { dist[0] = d2; nid[0] = mj; }
      }
    }
  }
  const size_t off = (((size_t)b * NN + n) * 8 + cz) * KK;
#pragma unroll
  for (int i = 0; i < KK; ++i) { partd[off + i] = dist[i]; parti[off + i] = nid[i]; }
}

// ---------------- merge 8 sorted 16-lists -> global top-16 (lexicographic (d, idx)) ----------------
__global__ __launch_bounds__(256) void knn_merge_kernel(const float* __restrict__ partd,
                                                        const int* __restrict__ parti,
                                                        int* __restrict__ idx) {
  const int g = blockIdx.x * 256 + threadIdx.x;  // global point
  const float* pd = partd + (size_t)g * 128;
  const int* pi = parti + (size_t)g * 128;
  int h[8];
#pragma unroll
  for (int c = 0; c < 8; ++c) h[c] = 0;
  int* out = idx + (size_t)g * KK;
  for (int o = 0; o < KK; ++o) {
    float bd = FLT_MAX;
    int bi = 0x7fffffff, bc = 0;
#pragma unroll
    for (int c = 0; c < 8; ++c) {
      const bool ok = h[c] < KK;
      const float d = ok ? pd[c * KK + h[c]] : FLT_MAX;
      const int ii = ok ? pi[c * KK + h[c]] : 0x7fffffff;
      const bool better = (d < bd) || (d == bd && ii < bi);
      bd = better ? d : bd;
      bi = better ? ii : bi;
      bc = better ? c : bc;
    }
    out[o] = bi;
#pragma unroll
    for (int c = 0; c < 8; ++c) h[c] += (bc == c) ? 1 : 0;
  }
}

// ---------------- tay[l][p][t][k] = w1_l @ taylor(rel) + b1_l ----------------
__global__ __launch_bounds__(256) void taylor_kernel(
    const float* __restrict__ pc, const int* __restrict__ idx,
    const float* __restrict__ w1_1, const float* __restrict__ b1_1,
    const float* __restrict__ w1_2, const float* __restrict__ b1_2,
    const float* __restrict__ w1_3, const float* __restrict__ b1_3,
    const float* __restrict__ w1_4, const float* __restrict__ b1_4,
    float* __restrict__ tay) {
  const int i = blockIdx.x * 256 + threadIdx.x;  // (p, k)
  if (i >= NPTS * KK) return;
  const int k = i & (KK - 1);
  const int p = i >> 4;
  const int n = p & (NN - 1);
  const int b = p >> 12;
  const float* pcb = pc + (size_t)b * NN * 6;
  const int m = idx[i];
  const float x = pcb[m * 6 + 0] - pcb[n * 6 + 0];
  const float y = pcb[m * 6 + 1] - pcb[n * 6 + 1];
  const float z = pcb[m * 6 + 2] - pcb[n * 6 + 2];
  float tb[20];
  tb[0] = 1.0f; tb[1] = x; tb[2] = y; tb[3] = z;
  tb[4] = x * x; tb[5] = x * y; tb[6] = x * z;
  tb[7] = y * y; tb[8] = y * z; tb[9] = z * z;
  tb[10] = tb[4] * x; tb[11] = tb[4] * y; tb[12] = tb[4] * z;
  tb[13] = tb[5] * y; tb[14] = tb[5] * z; tb[15] = tb[6] * z;
  tb[16] = tb[7] * y; tb[17] = tb[7] * z; tb[18] = tb[8] * z; tb[19] = tb[9] * z;
  const float* w1s[4] = {w1_1, w1_2, w1_3, w1_4};
  const float* b1s[4] = {b1_1, b1_2, b1_3, b1_4};
#pragma unroll
  for (int l = 0; l < 4; ++l) {
    const float* w1 = w1s[l];
    const float* b1 = b1s[l];
#pragma unroll
    for (int c = 0; c < 3; ++c) {
      float s = b1[c];
#pragma unroll
      for (int j = 0; j < 20; ++j) s = fmaf(w1[c * 20 + j], tb[j], s);
      tay[(size_t)l * TSTRIDE + (size_t)p * 48 + c * 16 + k] = s;
    }
  }
}

// ---------------- spider conv via bf16 MFMA ----------------
// GEMM: out[o,p] = sum_q W[o,q] * F[q,p], q=(c,t,k) k-fastest (w2 native layout).
// Tile: 64 points x 128 outs, BK=32, 4 waves (each 64o x 32p = 4x2 frags of 16x16x32).
// A (bf16 weights, padded rows) via global_load_lds; B built in LDS per step:
// F[q,p] = feat[c, idx[p,k]] * tay[p,t,k], fp32 mul then RNE->bf16.
template <int CIN, int COUT>
__global__ __launch_bounds__(256) void conv_mfma_kernel(
    const float* __restrict__ fin, int fin_bstride, int cstride, int pstride,
    const short* __restrict__ wb, const float* __restrict__ b2,
    const float* __restrict__ tayl, const int* __restrict__ idx,
    float* __restrict__ fout, int fout_bstride) {
  constexpr int QTOT = CIN * 48;
  constexpr int STEPS = QTOT / 32;
  __shared__ __align__(16) short As[128 * 32];   // [o_local][kk] 8 KB
  __shared__ __align__(16) short Bs[64 * 32];    // [p_local][kk] 4 KB
  __shared__ __align__(16) float tayS[64 * 48];  // [p_local][t][k] 12 KB
  const int t = threadIdx.x;
  const int pbase = blockIdx.x * 64;
  const int obase = blockIdx.y * 128;
  const int b = pbase >> 12;
  const int nbase = pbase & (NN - 1);
  // ---- stage tay tile (read-only for whole K-loop) ----
  {
    const float* ts = tayl + (size_t)pbase * 48;
#pragma unroll
    for (int i = 0; i < 3; ++i) {
      const int f = t * 4 + i * 1024;
      *(float4*)&tayS[f] = *(const float4*)&ts[f];
    }
  }
  // ---- persistent B-build state: thread t owns Bs[p_loc][sub*8 .. +8) ----
  const int p_loc = t >> 2;
  const int sub = t & 3;
  const int subh = sub >> 1;
  const int k0 = (sub & 1) * 8;
  int offs[8];
  {
    const int* mip = idx + ((size_t)(pbase + p_loc)) * KK + k0;
    const int4 a = *(const int4*)mip;
    const int4 c4 = *(const int4*)(mip + 4);
    offs[0] = a.x * pstride; offs[1] = a.y * pstride;
    offs[2] = a.z * pstride; offs[3] = a.w * pstride;
    offs[4] = c4.x * pstride; offs[5] = c4.y * pstride;
    offs[6] = c4.z * pstride; offs[7] = c4.w * pstride;
  }
  const float* finb = fin + (size_t)b * fin_bstride;
  // ---- A staging pointers (global_load_lds, 16B/lane, lane-contiguous LDS) ----
  const short* aw0 = wb + (size_t)(obase + (t >> 2)) * QTOT + (t & 3) * 8;
  const short* aw1 = aw0 + (size_t)64 * QTOT;
  short* lA0 = &As[t * 8];
  short* lA1 = &As[64 * 32 + t * 8];
  // ---- wave mapping ----
  const int lane = t & 63;
  const int w = t >> 6;
  const int wm = w & 1;   // o half (64)
  const int wn = w >> 1;  // p half (32)
  const int fr = lane & 15;
  const int fk = lane >> 4;
  f32x4 acc[4][2];
#pragma unroll
  for (int i = 0; i < 4; ++i)
#pragma unroll
    for (int j = 0; j < 2; ++j) acc[i][j] = (f32x4)(0.0f);
  // prefetch gathers for step 0
  float fv[8];
  {
    const int ct = subh;  // 2*0 + subh
    const int c = ct / 3;
    const float* fc = finb + (size_t)c * cstride;
#pragma unroll
    for (int j = 0; j < 8; ++j) fv[j] = fc[offs[j]];
  }
  __syncthreads();  // tayS ready
#pragma unroll 1
  for (int s = 0; s < STEPS; ++s) {
    // A stage (async to LDS)
    __builtin_amdgcn_global_load_lds(
        (const __attribute__((address_space(1))) u32*)(aw0 + s * 32),
        (__attribute__((address_space(3))) u32*)lA0, 16, 0, 0);
    __builtin_amdgcn_global_load_lds(
        (const __attribute__((address_space(1))) u32*)(aw1 + s * 32),
        (__attribute__((address_space(3))) u32*)lA1, 16, 0, 0);
    // B build from prefetched gathers
    const int ct = 2 * s + subh;
    const int c = ct / 3;
    const int tt = ct - c * 3;
    float tv[8];
    *(float4*)&tv[0] = *(const float4*)&tayS[p_loc * 48 + tt * 16 + k0];
    *(float4*)&tv[4] = *(const float4*)&tayS[p_loc * 48 + tt * 16 + k0 + 4];
    bf16x8 pk;
#pragma unroll
    for (int j = 0; j < 8; ++j) pk[j] = (short)f2bf(fv[j] * tv[j]);
    *(bf16x8*)&Bs[t * 8] = pk;
    // prefetch gathers for next step (overlaps MFMA + barrier)
    {
      const int sn = (s + 1 < STEPS) ? s + 1 : s;
      const int ctn = 2 * sn + subh;
      const int cn = ctn / 3;
      const float* fc = finb + (size_t)cn * cstride;
#pragma unroll
      for (int j = 0; j < 8; ++j) fv[j] = fc[offs[j]];
    }
    __syncthreads();  // A loads + B writes visible
    bf16x8 af[4], bfr[2];
#pragma unroll
    for (int i = 0; i < 4; ++i)
      af[i] = *(const bf16x8*)&As[(wm * 64 + i * 16 + fr) * 32 + fk * 8];
#pragma unroll
    for (int j = 0; j < 2; ++j)
      bfr[j] = *(const bf16x8*)&Bs[(wn * 32 + j * 16 + fr) * 32 + fk * 8];
#pragma unroll
    for (int i = 0; i < 4; ++i)
#pragma unroll
      for (int j = 0; j < 2; ++j)
        acc[i][j] = __builtin_amdgcn_mfma_f32_16x16x32_bf16(af[i], bfr[j], acc[i][j], 0, 0, 0);
    __syncthreads();  // frag reads done before next overwrite
  }
  // ---- epilogue: bias + relu, fp32 store ----
  float* outb = fout + (size_t)b * fout_bstride;
#pragma unroll
  for (int i = 0; i < 4; ++i) {
#pragma unroll
    for (int r = 0; r < 4; ++r) {
      const int o = obase + wm * 64 + i * 16 + fk * 4 + r;
      if (o < COUT) {
        const float bias = b2[o];
#pragma unroll
        for (int j = 0; j < 2; ++j) {
          const int p_l = wn * 32 + j * 16 + fr;
          outb[(size_t)o * NN + nbase + p_l] = fmaxf(acc[i][j][r] + bias, 0.0f);
        }
      }
    }
  }
}

// ---------------- top-2 over N per (b, channel) ----------------
__global__ __launch_bounds__(256) void top2_kernel(const float* __restrict__ pf,
                                                   float* __restrict__ cat) {
  const int row = blockIdx.x;  // b*480 + ch
  const float* p = pf + (size_t)row * NN;
  float m1 = -FLT_MAX, m2 = -FLT_MAX;
  for (int i = threadIdx.x; i < NN; i += 256) {
    const float v = p[i];
    if (v > m1) { m2 = m1; m1 = v; }
    else if (v > m2) m2 = v;
  }
#pragma unroll
  for (int off = 32; off > 0; off >>= 1) {
    const float o1 = __shfl_down(m1, off, 64);
    const float o2 = __shfl_down(m2, off, 64);
    const float nm1 = fmaxf(m1, o1);
    const float nm2 = fmaxf(fminf(m1, o1), fmaxf(m2, o2));
    m1 = nm1; m2 = nm2;
  }
  __shared__ float s1[4], s2[4];
  const int wid = threadIdx.x >> 6;
  if ((threadIdx.x & 63) == 0) { s1[wid] = m1; s2[wid] = m2; }
  __syncthreads();
  if (threadIdx.x == 0) {
    m1 = s1[0]; m2 = s2[0];
#pragma unroll
    for (int w = 1; w < 4; ++w) {
      const float o1 = s1[w], o2 = s2[w];
      const float nm1 = fmaxf(m1, o1);
      const float nm2 = fmaxf(fminf(m1, o1), fmaxf(m2, o2));
      m1 = nm1; m2 = nm2;
    }
    const int b = row / 480, ch = row % 480;
    cat[b * 960 + ch * 2 + 0] = m1;
    cat[b * 960 + ch * 2 + 1] = m2;
  }
}

extern "C" void kernel_launch(void* const* d_in, const int* in_sizes, int n_in,
                              void* d_out, int out_size, void* d_ws, size_t ws_size,
                              hipStream_t stream) {
  const float* pc = (const float*)d_in[0];
  const float* w1s[4]; const float* b1s[4]; const float* w2s[4]; const float* b2s[4];
  for (int l = 0; l < 4; ++l) {
    w1s[l] = (const float*)d_in[1 + 4 * l];
    b1s[l] = (const float*)d_in[2 + 4 * l];
    w2s[l] = (const float*)d_in[3 + 4 * l];
    b2s[l] = (const float*)d_in[4 + 4 * l];
  }
  // workspace layout (floats): idx | tay (4 layers) | wbf (bf16)
  // knn partials (16 MB) alias tay+wbf and are fully consumed before those are written.
  float* ws = (float*)d_ws;
  int* idx = (int*)ws;                              // 262144 ints
  float* tay = ws + 262144;                         // 4*786432 floats
  short* wbf = (short*)(ws + 262144 + 4 * TSTRIDE); // 2199552 shorts
  float* partd = tay;                               // 2097152 floats (alias)
  int* parti = (int*)(tay + 2097152);               // 2097152 ints  (alias)
  short* wb1 = wbf;
  short* wb2 = wb1 + 128 * 288;
  short* wb3 = wb2 + 128 * 1536;
  short* wb4 = wb3 + 128 * 3072;
  float* cat = (float*)d_out;                       // B*960
  float* pf = (float*)d_out + BB * 960;             // (B, 480, N)
  const int pfstride = 480 * NN;

  knn_part_kernel<<<dim3(NN / 256, BB, 8), 256, 0, stream>>>(pc, partd, parti);
  knn_merge_kernel<<<dim3(NPTS / 256), 256, 0, stream>>>(partd, parti, idx);
  wcvt_kernel<<<dim3((128 * 288 + 255) / 256), 256, 0, stream>>>(w2s[0], wb1, 32, 128 * 288, 288);
  wcvt_kernel<<<dim3((128 * 1536 + 255) / 256), 256, 0, stream>>>(w2s[1], wb2, 64, 128 * 1536, 1536);
  wcvt_kernel<<<dim3((128 * 3072 + 255) / 256), 256, 0, stream>>>(w2s[2], wb3, 128, 128 * 3072, 3072);
  wcvt_kernel<<<dim3((256 * 6144 + 255) / 256), 256, 0, stream>>>(w2s[3], wb4, 256, 256 * 6144, 6144);
  taylor_kernel<<<dim3(NPTS * KK / 256), 256, 0, stream>>>(
      pc, idx, w1s[0], b1s[0], w1s[1], b1s[1], w1s[2], b1s[2], w1s[3], b1s[3], tay);
  conv_mfma_kernel<6, 32><<<dim3(NPTS / 64, 1), 256, 0, stream>>>(
      pc, NN * 6, 1, 6, wb1, b2s[0], tay + 0 * (size_t)TSTRIDE, idx, pf + (size_t)0 * NN, pfstride);
  conv_mfma_kernel<32, 64><<<dim3(NPTS / 64, 1), 256, 0, stream>>>(
      pf + (size_t)0 * NN, pfstride, NN, 1, wb2, b2s[1], tay + 1 * (size_t)TSTRIDE, idx,
      pf + (size_t)32 * NN, pfstride);
  conv_mfma_kernel<64, 128><<<dim3(NPTS / 64, 1), 256, 0, stream>>>(
      pf + (size_t)32 * NN, pfstride, NN, 1, wb3, b2s[2], tay + 2 * (size_t)TSTRIDE, idx,
      pf + (size_t)96 * NN, pfstride);
  conv_mfma_kernel<128, 256><<<dim3(NPTS / 64, 2), 256, 0, stream>>>(
      pf + (size_t)96 * NN, pfstride, NN, 1, wb4, b2s[3], tay + 3 * (size_t)TSTRIDE, idx,
      pf + (size_t)224 * NN, pfstride);
  top2_kernel<<<dim3(BB * 480), 256, 0, stream>>>(pf, cat);
}

// Round 3
// 521.946 us; speedup vs baseline: 4.8475x; 1.4247x over previous
//
#include <hip/hip_runtime.h>
#include <hip/hip_fp16.h>
#include <cfloat>

#define BB 4
#define NN 4096
#define KK 16
#define NPTS (BB * NN)      // 16384
#define NT48 (48 * NPTS)    // per-layer tay floats, layout [48][NPTS]

typedef __attribute__((ext_vector_type(8))) _Float16 f16x8;
typedef __attribute__((ext_vector_type(4))) float f32x4;
typedef unsigned int u32;

__device__ __forceinline__ short f2h(float v) {
  __half h = __float2half_rn(v);
  return __half_as_short(h);
}
__device__ __forceinline__ u32 mulh2(u32 a, __half2 t) {
  __half2 x = __hmul2(*(__half2*)&a, t);
  return *(u32*)&x;
}

// ---------------- KNN partials: top-16 within candidate chunk cz (512 cands) ----------------
__global__ __launch_bounds__(256) void knn_part_kernel(const float* __restrict__ pc,
                                                       float* __restrict__ partd,
                                                       int* __restrict__ parti) {
  __shared__ float4 sc[256];
  const int b = blockIdx.y;
  const int cz = blockIdx.z;
  const int n = blockIdx.x * 256 + threadIdx.x;
  const float* pcb = pc + (size_t)b * NN * 6;
  const float xn = pcb[n * 6 + 0];
  const float yn = pcb[n * 6 + 1];
  const float zn = pcb[n * 6 + 2];
  const float sqn = xn * xn + yn * yn + zn * zn;
  float dist[KK];
  int nid[KK];
#pragma unroll
  for (int i = 0; i < KK; ++i) { dist[i] = FLT_MAX; nid[i] = 0; }
  for (int t4 = 0; t4 < 2; ++t4) {
    const int base = cz * 512 + t4 * 256;
    const int m0 = base + threadIdx.x;
    float x = pcb[m0 * 6 + 0];
    float y = pcb[m0 * 6 + 1];
    float z = pcb[m0 * 6 + 2];
    __syncthreads();
    sc[threadIdx.x] = make_float4(x, y, z, x * x + y * y + z * z);
    __syncthreads();
    for (int j = 0; j < 256; ++j) {
      const float4 q = sc[j];
      const float d2 = sqn + q.w - 2.0f * (xn * q.x + yn * q.y + zn * q.z);
      if (d2 < dist[KK - 1]) {  // strict: ties keep earlier (lower) index
        const int mj = base + j;
        bool c_hi = true;
#pragma unroll
        for (int i = KK - 1; i > 0; --i) {
          const bool c_lo = d2 < dist[i - 1];
          const float di = c_lo ? dist[i - 1] : (c_hi ? d2 : dist[i]);
          const int ii = c_lo ? nid[i - 1] : (c_hi ? mj : nid[i]);
          dist[i] = di; nid[i] = ii;
          c_hi = c_lo;
        }
        if (c_hi) { dist[0] = d2; nid[0] = mj; }
      }
    }
  }
  const size_t off = (((size_t)b * NN + n) * 8 + cz) * KK;
#pragma unroll
  for (int i = 0; i < KK; ++i) { partd[off + i] = dist[i]; parti[off + i] = nid[i]; }
}

// ---------------- merge 8 sorted 16-lists -> global top-16 ----------------
__global__ __launch_bounds__(256) void knn_merge_kernel(const float* __restrict__ partd,
                                                        const int* __restrict__ parti,
                                                        int* __restrict__ idx) {
  const int g = blockIdx.x * 256 + threadIdx.x;
  const float* pd = partd + (size_t)g * 128;
  const int* pi = parti + (size_t)g * 128;
  int h[8];
#pragma unroll
  for (int c = 0; c < 8; ++c) h[c] = 0;
  int* out = idx + (size_t)g * KK;
  for (int o = 0; o < KK; ++o) {
    float bd = FLT_MAX;
    int bi = 0x7fffffff, bc = 0;
#pragma unroll
    for (int c = 0; c < 8; ++c) {
      const bool ok = h[c] < KK;
      const float d = ok ? pd[c * KK + h[c]] : FLT_MAX;
      const int ii = ok ? pi[c * KK + h[c]] : 0x7fffffff;
      const bool better = (d < bd) || (d == bd && ii < bi);
      bd = better ? d : bd;
      bi = better ? ii : bi;
      bc = better ? c : bc;
    }
    out[o] = bi;
#pragma unroll
    for (int c = 0; c < 8; ++c) h[c] += (bc == c) ? 1 : 0;
  }
}

// ---------------- pc -> ft0 f16 [p][8] (6 channels + pad) ----------------
__global__ __launch_bounds__(256) void pc2ft_kernel(const float* __restrict__ pc,
                                                    short* __restrict__ ft0) {
  const int i = blockIdx.x * 256 + threadIdx.x;
  if (i >= NPTS) return;
  const float* s = pc + (size_t)i * 6;
  short* d = ft0 + (size_t)i * 8;
#pragma unroll
  for (int c = 0; c < 6; ++c) d[c] = f2h(s[c]);
  d[6] = 0; d[7] = 0;
}

// ---------------- weights fp32 (o,(c,t),k) -> f16 permuted [o][(t,k,c)] padded ----------------
__global__ __launch_bounds__(256) void wcvt_kernel(const float* __restrict__ w2,
                                                   short* __restrict__ wb,
                                                   int CIN, int COUT, int CPAD, int LOGC,
                                                   int total8) {
  const int i = blockIdx.x * 256 + threadIdx.x;
  if (i >= total8) return;
  const int q8 = i * 8;
  const int QT = CPAD * 48;
  const int o = q8 / QT;
  const int r = q8 - o * QT;
  const int kq = r >> LOGC;
  const int c0 = r & (CPAD - 1);
  const int tt = kq >> 4;
  const int k = kq & 15;
  short h[8];
#pragma unroll
  for (int j = 0; j < 8; ++j) {
    const int c = c0 + j;
    const float v = (o < COUT && c < CIN) ? w2[(size_t)o * CIN * 48 + (c * 3 + tt) * 16 + k] : 0.0f;
    h[j] = f2h(v);
  }
  short* d = wb + (size_t)o * QT + r;
#pragma unroll
  for (int j = 0; j < 8; ++j) d[j] = h[j];
}

// ---------------- tay_g[l][t*16+k][p] = (w1_l @ taylor(rel) + b1_l) ----------------
__global__ __launch_bounds__(256) void taylor_kernel(
    const float* __restrict__ pc, const int* __restrict__ idx,
    const float* __restrict__ w1_1, const float* __restrict__ b1_1,
    const float* __restrict__ w1_2, const float* __restrict__ b1_2,
    const float* __restrict__ w1_3, const float* __restrict__ b1_3,
    const float* __restrict__ w1_4, const float* __restrict__ b1_4,
    float* __restrict__ tayg) {
  const int i = blockIdx.x * 256 + threadIdx.x;  // p fastest, then k
  if (i >= NPTS * KK) return;
  const int p = i & (NPTS - 1);
  const int k = i >> 14;
  const int n = p & (NN - 1);
  const int b = p >> 12;
  const float* pcb = pc + (size_t)b * NN * 6;
  const int m = idx[(size_t)p * KK + k];
  const float x = pcb[m * 6 + 0] - pcb[n * 6 + 0];
  const float y = pcb[m * 6 + 1] - pcb[n * 6 + 1];
  const float z = pcb[m * 6 + 2] - pcb[n * 6 + 2];
  float tb[20];
  tb[0] = 1.0f; tb[1] = x; tb[2] = y; tb[3] = z;
  tb[4] = x * x; tb[5] = x * y; tb[6] = x * z;
  tb[7] = y * y; tb[8] = y * z; tb[9] = z * z;
  tb[10] = tb[4] * x; tb[11] = tb[4] * y; tb[12] = tb[4] * z;
  tb[13] = tb[5] * y; tb[14] = tb[5] * z; tb[15] = tb[6] * z;
  tb[16] = tb[7] * y; tb[17] = tb[7] * z; tb[18] = tb[8] * z; tb[19] = tb[9] * z;
  const float* w1s[4] = {w1_1, w1_2, w1_3, w1_4};
  const float* b1s[4] = {b1_1, b1_2, b1_3, b1_4};
#pragma unroll
  for (int l = 0; l < 4; ++l) {
    const float* w1 = w1s[l];
    const float* b1 = b1s[l];
#pragma unroll
    for (int c = 0; c < 3; ++c) {
      float s = b1[c];
#pragma unroll
      for (int j = 0; j < 20; ++j) s = fmaf(w1[c * 20 + j], tb[j], s);
      tayg[(size_t)(l * 48 + c * 16 + k) * NPTS + p] = s;
    }
  }
}

// ---------------- spider conv via f16 MFMA; q=(t,k,c) c-fastest ----------------
// Tile: 64 points x OTILE outs, BK=32, 4 waves. A via global_load_lds (dbuf);
// B built per step: one 16B contiguous feat load x scalar tay, v_pk_mul_f16.
// Single __syncthreads per step.
template <int CPAD, int LOGC, int COUT, int OTILE>
__global__ __launch_bounds__(256) void conv_mfma_kernel(
    const char* __restrict__ ftin,        // f16 [NPTS][CPAD]
    const short* __restrict__ wb,         // f16 [OPAD][QTOT] permuted
    const float* __restrict__ b2,
    const float* __restrict__ tayg,       // f32 [48][NPTS] (this layer)
    const int* __restrict__ idx,
    float* __restrict__ pfout, int pfbstride,
    short* __restrict__ ftout, int CPADN) {
  constexpr int QTOT = CPAD * 48;
  constexpr int STEPS = QTOT / 32;
  constexpr int NJ = OTILE / 64;  // 2 (OTILE=128) or 1 (OTILE=64)
  constexpr int PW = 16 * NJ;
  __shared__ __align__(16) short As[2][OTILE * 32];
  __shared__ __align__(16) short Bs[2][64 * 32];
  __shared__ __align__(16) float tayS[48 * 64];
  __shared__ int idxS[16 * 64];
  const int t = threadIdx.x;
  const int pbase = blockIdx.x * 64;
  const int obase = blockIdx.y * OTILE;
  const int b = pbase >> 12;
  const int nbase = pbase & (NN - 1);
  const int p_loc = t >> 2;
  const int sub = t & 3;
  // ---- stage tay tile [48][64] (coalesced rows) ----
#pragma unroll
  for (int i = 0; i < 3; ++i) {
    const int f = i * 1024 + t * 4;
    *(float4*)&tayS[f] = *(const float4*)&tayg[(size_t)(f >> 6) * NPTS + pbase + (f & 63)];
  }
  // ---- stage neighbor byte-offsets ----
  {
    const int4 mi = *(const int4*)&idx[(size_t)(pbase + p_loc) * KK + sub * 4];
    const int gb = b << 12;
    idxS[(sub * 4 + 0) * 64 + p_loc] = (gb + mi.x) << (LOGC + 1);
    idxS[(sub * 4 + 1) * 64 + p_loc] = (gb + mi.y) << (LOGC + 1);
    idxS[(sub * 4 + 2) * 64 + p_loc] = (gb + mi.z) << (LOGC + 1);
    idxS[(sub * 4 + 3) * 64 + p_loc] = (gb + mi.w) << (LOGC + 1);
  }
  // ---- wave mapping ----
  const int lane = t & 63;
  const int w = t >> 6;
  const int wm = (NJ == 2) ? (w & 1) : 0;
  const int wn = (NJ == 2) ? (w >> 1) : w;
  const int fr = lane & 15;
  const int fk = lane >> 4;
  const short* aw = wb + (size_t)(obase + p_loc) * QTOT + sub * 8;
  f32x4 acc[4][NJ];
#pragma unroll
  for (int i = 0; i < 4; ++i)
#pragma unroll
    for (int j = 0; j < NJ; ++j) acc[i][j] = (f32x4)(0.0f);
  __syncthreads();  // tayS, idxS ready

  uint4 fv[2];
  float tv[2];
  auto pref = [&](int ss, int slot) {
    const int seg = ss * 32 + sub * 8;
    const int kq = seg >> LOGC;
    const int c0 = seg & (CPAD - 1);
    const int moff = idxS[(kq & 15) * 64 + p_loc];
    tv[slot] = tayS[kq * 64 + p_loc];
    fv[slot] = *(const uint4*)(ftin + moff + (c0 << 1));
  };
  auto build = [&](int slot, int dstph) {
    const __half2 t2 = __half2half2(__float2half_rn(tv[slot]));
    const uint4 f = fv[slot];
    uint4 r;
    r.x = mulh2(f.x, t2); r.y = mulh2(f.y, t2);
    r.z = mulh2(f.z, t2); r.w = mulh2(f.w, t2);
    const int chunk = sub ^ ((p_loc >> 1) & 3);
    *(uint4*)&Bs[dstph][p_loc * 32 + chunk * 8] = r;
  };
  auto dmaA = [&](int ss, int dstph) {
#pragma unroll
    for (int h = 0; h < NJ; ++h)
      __builtin_amdgcn_global_load_lds(
          (const __attribute__((address_space(1))) u32*)(aw + (size_t)h * 64 * QTOT + ss * 32),
          (__attribute__((address_space(3))) u32*)&As[dstph][h * 2048 + t * 8], 16, 0, 0);
  };
  // ---- prime ----
  pref(0, 0);
  dmaA(0, 0);
  pref(1, 1);
  build(0, 0);
  __syncthreads();  // drains DMA(0), feat(1); Bs[0] visible
#pragma unroll 2
  for (int s = 0; s < STEPS; ++s) {
    const int ph = s & 1;
    if (s + 2 < STEPS) pref(s + 2, s & 1);       // slot (s+2)&1 == s&1
    if (s + 1 < STEPS) dmaA(s + 1, ph ^ 1);
    f16x8 af[4];
#pragma unroll
    for (int i = 0; i < 4; ++i)
      af[i] = *(const f16x8*)&As[ph][(wm * 64 + i * 16 + fr) * 32 + fk * 8];
    f16x8 bfr[NJ];
    const int bch = (fk ^ ((fr >> 1) & 3)) * 8;
#pragma unroll
    for (int j = 0; j < NJ; ++j)
      bfr[j] = *(const f16x8*)&Bs[ph][(wn * PW + j * 16 + fr) * 32 + bch];
    if (s + 1 < STEPS) build((s + 1) & 1, ph ^ 1);
#pragma unroll
    for (int i = 0; i < 4; ++i)
#pragma unroll
      for (int j = 0; j < NJ; ++j)
        acc[i][j] = __builtin_amdgcn_mfma_f32_16x16x32_f16(af[i], bfr[j], acc[i][j], 0, 0, 0);
    if (s + 1 < STEPS) __syncthreads();
  }
  // ---- epilogue: bias + relu; fp32 -> pf, f16 -> ft_next ----
  float* outb = pfout + (size_t)b * pfbstride;
#pragma unroll
  for (int i = 0; i < 4; ++i) {
    const int o0 = obase + wm * 64 + i * 16 + fk * 4;
    if (o0 < COUT) {
      const float4 b4 = *(const float4*)&b2[o0];
#pragma unroll
      for (int j = 0; j < NJ; ++j) {
        const int p_l = wn * PW + j * 16 + fr;
        const float v0 = fmaxf(acc[i][j][0] + b4.x, 0.0f);
        const float v1 = fmaxf(acc[i][j][1] + b4.y, 0.0f);
        const float v2 = fmaxf(acc[i][j][2] + b4.z, 0.0f);
        const float v3 = fmaxf(acc[i][j][3] + b4.w, 0.0f);
        outb[(size_t)(o0 + 0) * NN + nbase + p_l] = v0;
        outb[(size_t)(o0 + 1) * NN + nbase + p_l] = v1;
        outb[(size_t)(o0 + 2) * NN + nbase + p_l] = v2;
        outb[(size_t)(o0 + 3) * NN + nbase + p_l] = v3;
        if (ftout) {
          const __half2 h01 = __floats2half2_rn(v0, v1);
          const __half2 h23 = __floats2half2_rn(v2, v3);
          uint2 pk;
          pk.x = *(const u32*)&h01;
          pk.y = *(const u32*)&h23;
          *(uint2*)&ftout[(size_t)(pbase + p_l) * CPADN + o0] = pk;
        }
      }
    }
  }
}

// ---------------- top-2 over N per (b, channel) ----------------
__global__ __launch_bounds__(256) void top2_kernel(const float* __restrict__ pf,
                                                   float* __restrict__ cat) {
  const int row = blockIdx.x;  // b*480 + ch
  const float* p = pf + (size_t)row * NN;
  float m1 = -FLT_MAX, m2 = -FLT_MAX;
  for (int i = threadIdx.x; i < NN; i += 256) {
    const float v = p[i];
    if (v > m1) { m2 = m1; m1 = v; }
    else if (v > m2) m2 = v;
  }
#pragma unroll
  for (int off = 32; off > 0; off >>= 1) {
    const float o1 = __shfl_down(m1, off, 64);
    const float o2 = __shfl_down(m2, off, 64);
    const float nm1 = fmaxf(m1, o1);
    const float nm2 = fmaxf(fminf(m1, o1), fmaxf(m2, o2));
    m1 = nm1; m2 = nm2;
  }
  __shared__ float s1[4], s2[4];
  const int wid = threadIdx.x >> 6;
  if ((threadIdx.x & 63) == 0) { s1[wid] = m1; s2[wid] = m2; }
  __syncthreads();
  if (threadIdx.x == 0) {
    m1 = s1[0]; m2 = s2[0];
#pragma unroll
    for (int w = 1; w < 4; ++w) {
      const float o1 = s1[w], o2 = s2[w];
      const float nm1 = fmaxf(m1, o1);
      const float nm2 = fmaxf(fminf(m1, o1), fmaxf(m2, o2));
      m1 = nm1; m2 = nm2;
    }
    const int b = row / 480, ch = row % 480;
    cat[b * 960 + ch * 2 + 0] = m1;
    cat[b * 960 + ch * 2 + 1] = m2;
  }
}

extern "C" void kernel_launch(void* const* d_in, const int* in_sizes, int n_in,
                              void* d_out, int out_size, void* d_ws, size_t ws_size,
                              hipStream_t stream) {
  const float* pc = (const float*)d_in[0];
  const float* w1s[4]; const float* b1s[4]; const float* w2s[4]; const float* b2s[4];
  for (int l = 0; l < 4; ++l) {
    w1s[l] = (const float*)d_in[1 + 4 * l];
    b1s[l] = (const float*)d_in[2 + 4 * l];
    w2s[l] = (const float*)d_in[3 + 4 * l];
    b2s[l] = (const float*)d_in[4 + 4 * l];
  }
  // ---- workspace layout (bytes) ----
  char* W = (char*)d_ws;
  int* idx = (int*)W;                                  // 1,048,576
  float* tayg = (float*)(W + 1048576);                 // 4 x 3,145,728 = 12,582,912
  short* wb1 = (short*)(W + 13631488);                 // 64*384    f16 =    49,152 B
  short* wb2 = wb1 + 64 * 384;                         // 64*1536       =   196,608 B
  short* wb3 = wb2 + 64 * 1536;                        // 128*3072      =   786,432 B
  short* wb4 = wb3 + 128 * 3072;                       // 256*6144      = 3,145,728 B
  short* ft0 = (short*)(W + 17809408);                 // 16384*8  f16  =   262,144 B
  short* ft1 = (short*)(W + 18071552);                 // 16384*32      = 1,048,576 B
  // aliases (lifetime-checked):
  float* partd = tayg;                                 // knn partials (16 MB), consumed pre-taylor/wcvt
  int* parti = (int*)(tayg + 2097152);
  short* ft2 = (short*)(W + 1048576);                  // 2 MB in tay_g[0]; written L2-epi (tay_g[0] dead)
  short* ft3 = (short*)(W + 1048576 + 2097152);        // 4 MB in tay_g[0..1] tail; written L3-epi
  float* cat = (float*)d_out;                          // B*960
  float* pf = (float*)d_out + BB * 960;                // (B, 480, N)
  const int pfstride = 480 * NN;

  knn_part_kernel<<<dim3(NN / 256, BB, 8), 256, 0, stream>>>(pc, partd, parti);
  knn_merge_kernel<<<dim3(NPTS / 256), 256, 0, stream>>>(partd, parti, idx);
  pc2ft_kernel<<<dim3(NPTS / 256), 256, 0, stream>>>(pc, ft0);
  wcvt_kernel<<<dim3((64 * 384 / 8 + 255) / 256), 256, 0, stream>>>(w2s[0], wb1, 6, 32, 8, 3, 64 * 384 / 8);
  wcvt_kernel<<<dim3((64 * 1536 / 8 + 255) / 256), 256, 0, stream>>>(w2s[1], wb2, 32, 64, 32, 5, 64 * 1536 / 8);
  wcvt_kernel<<<dim3((128 * 3072 / 8 + 255) / 256), 256, 0, stream>>>(w2s[2], wb3, 64, 128, 64, 6, 128 * 3072 / 8);
  wcvt_kernel<<<dim3((256 * 6144 / 8 + 255) / 256), 256, 0, stream>>>(w2s[3], wb4, 128, 256, 128, 7, 256 * 6144 / 8);
  taylor_kernel<<<dim3(NPTS * KK / 256), 256, 0, stream>>>(
      pc, idx, w1s[0], b1s[0], w1s[1], b1s[1], w1s[2], b1s[2], w1s[3], b1s[3], tayg);
  conv_mfma_kernel<8, 3, 32, 64><<<dim3(NPTS / 64, 1), 256, 0, stream>>>(
      (const char*)ft0, wb1, b2s[0], tayg + 0 * (size_t)NT48, idx,
      pf + (size_t)0 * NN, pfstride, ft1, 32);
  conv_mfma_kernel<32, 5, 64, 64><<<dim3(NPTS / 64, 1), 256, 0, stream>>>(
      (const char*)ft1, wb2, b2s[1], tayg + 1 * (size_t)NT48, idx,
      pf + (size_t)32 * NN, pfstride, ft2, 64);
  conv_mfma_kernel<64, 6, 128, 64><<<dim3(NPTS / 64, 2), 256, 0, stream>>>(
      (const char*)ft2, wb3, b2s[2], tayg + 2 * (size_t)NT48, idx,
      pf + (size_t)96 * NN, pfstride, ft3, 128);
  conv_mfma_kernel<128, 7, 256, 128><<<dim3(NPTS / 64, 2), 256, 0, stream>>>(
      (const char*)ft3, wb4, b2s[3], tayg + 3 * (size_t)NT48, idx,
      pf + (size_t)224 * NN, pfstride, nullptr, 0);
  top2_kernel<<<dim3(BB * 480), 256, 0, stream>>>(pf, cat);
}